// Round 2
// baseline (497.074 us; speedup 1.0000x reference)
//
#include <hip/hip_runtime.h>

// EMARecurrent: y[b,t,:] = a*x[b,t,:] + (1-a)*y[b,t-1,:], y[b,-1,:] = hidden[b,0,:]
// B=16, T=4096, D=1024 — all fp32 (reference dtypes; harness honors them).
//
// Chunked parallel scan (exact for linear recurrences):
//   chunk length L=64, C=64 chunks/sequence.
//   A_c = chunk-local EMA starting from 0 (pass 1)
//   P_c = carry-in state for chunk c: P_0 = h0, P_{c+1} = A_c + f^L * P_c (pass 2)
//   y within chunk c = plain recurrence started from P_c (pass 3)

#define B_ 16
#define T_ 4096
#define D_ 1024
#define C_ 64              // chunks per sequence
#define L_ (T_ / C_)       // 64 timesteps per chunk
#define D4 (D_ / 4)        // 256 float4 lanes cover one row

// ---- Pass 1: per-chunk local aggregate A_c (EMA from h=0 over L steps) ----
__global__ __launch_bounds__(256) void ema_chunk_agg(
    const float* __restrict__ x,
    const float* __restrict__ alpha,
    float* __restrict__ agg)
{
    const float a = fabsf(alpha[0]);
    const float f = 1.0f - a;

    const int blk  = blockIdx.x;        // b*C_ + c
    const int b    = blk >> 6;          // / C_
    const int c    = blk & (C_ - 1);    // % C_
    const int lane = threadIdx.x;       // 0..255, 4 d's each

    const size_t base = ((size_t)b * T_ + (size_t)c * L_) * D_ + (size_t)lane * 4;
    const float4* xv = reinterpret_cast<const float4*>(x + base);

    float4 h = float4{0.f, 0.f, 0.f, 0.f};

#pragma unroll 8
    for (int i = 0; i < L_; ++i) {
        float4 v = xv[(size_t)i * D4];
        h.x = a * v.x + f * h.x;
        h.y = a * v.y + f * h.y;
        h.z = a * v.z + f * h.z;
        h.w = a * v.w + f * h.w;
    }

    reinterpret_cast<float4*>(agg + ((size_t)b * C_ + c) * D_)[lane] = h;
}

// ---- Pass 2: in-place scan over chunks; agg[c] becomes carry-in P_c ----
__global__ __launch_bounds__(256) void ema_chunk_scan(
    float* __restrict__ agg,
    const float* __restrict__ hidden,
    const float* __restrict__ alpha)
{
    const float a = fabsf(alpha[0]);
    const float f = 1.0f - a;
    float F = 1.0f;
#pragma unroll
    for (int i = 0; i < L_; ++i) F *= f;     // f^L

    const int tid = blockIdx.x * blockDim.x + threadIdx.x;  // 0..B_*D4-1
    const int b   = tid >> 8;                // / D4 (D4 == 256)
    const int d4  = tid & (D4 - 1);          // % D4

    float4 p = reinterpret_cast<const float4*>(hidden + (size_t)b * D_)[d4];  // h0

    float4* A = reinterpret_cast<float4*>(agg + (size_t)b * C_ * D_) + d4;

#pragma unroll 4
    for (int c = 0; c < C_; ++c) {
        float4* Ac = A + (size_t)c * D4;
        float4 v = *Ac;      // A_c
        *Ac = p;             // overwrite with carry-in P_c
        p.x = v.x + F * p.x;
        p.y = v.y + F * p.y;
        p.z = v.z + F * p.z;
        p.w = v.w + F * p.w;
    }
}

// ---- Pass 3: recompute chunk EMA from correct carry-in, write y ----
__global__ __launch_bounds__(256) void ema_apply(
    const float* __restrict__ x,
    const float* __restrict__ pref,
    const float* __restrict__ alpha,
    float* __restrict__ y)
{
    const float a = fabsf(alpha[0]);
    const float f = 1.0f - a;

    const int blk  = blockIdx.x;
    const int b    = blk >> 6;
    const int c    = blk & (C_ - 1);
    const int lane = threadIdx.x;

    float4 h = reinterpret_cast<const float4*>(pref + ((size_t)b * C_ + c) * D_)[lane];

    const size_t base = ((size_t)b * T_ + (size_t)c * L_) * D_ + (size_t)lane * 4;
    const float4* xv = reinterpret_cast<const float4*>(x + base);
    float4*       yv = reinterpret_cast<float4*>(y + base);

#pragma unroll 4
    for (int i = 0; i < L_; ++i) {
        float4 v = xv[(size_t)i * D4];
        h.x = a * v.x + f * h.x;
        h.y = a * v.y + f * h.y;
        h.z = a * v.z + f * h.z;
        h.w = a * v.w + f * h.w;
        yv[(size_t)i * D4] = h;
    }
}

extern "C" void kernel_launch(void* const* d_in, const int* in_sizes, int n_in,
                              void* d_out, int out_size, void* d_ws, size_t ws_size,
                              hipStream_t stream) {
    const float* x      = (const float*)d_in[0];
    const float* hidden = (const float*)d_in[1];
    const float* alpha  = (const float*)d_in[2];
    float*       y      = (float*)d_out;

    float* agg = (float*)d_ws;   // B_*C_*D_ floats = 4 MB (scan done in place)

    ema_chunk_agg <<<B_ * C_, 256, 0, stream>>>(x, alpha, agg);
    ema_chunk_scan<<<(B_ * D4) / 256, 256, 0, stream>>>(agg, hidden, alpha);
    ema_apply     <<<B_ * C_, 256, 0, stream>>>(x, agg, alpha, y);
}